// Round 19
// baseline (185.656 us; speedup 1.0000x reference)
//
#include <hip/hip_runtime.h>

// ---------------- types ----------------
typedef __bf16 bf16x8 __attribute__((ext_vector_type(8)));
typedef float  f32x4  __attribute__((ext_vector_type(4)));

static __device__ __forceinline__ ushort f2bf(float f) {
    union { float f; unsigned u; } a; a.f = f;
    unsigned r = a.u + 0x7FFFu + ((a.u >> 16) & 1u);   // RNE
    return (ushort)(r >> 16);
}
static __device__ __forceinline__ ushort f2bf_hw(float f) {
    __bf16 b = (__bf16)f;                               // HW cvt (RNE), pairs -> cvt_pk
    return __builtin_bit_cast(ushort, b);
}
static __device__ __forceinline__ float bf2f(ushort u) {
    return __builtin_bit_cast(float, (unsigned)u << 16);
}

// ---------------- constants ----------------
#define TS  2048   // S
#define TD  1024   // D
#define TL  256    // L
#define TH  1024   // H
#define TNH 16
#define THD 64
#define TDF 4096   // 4*D
#define TQC 1280   // fused q|c output width (H + L)
#define ATT_CE 0.18033688f   // 0.125 * log2(e)
#define NSPLIT 8

#define GLD_LDS(gp, lp) \
    __builtin_amdgcn_global_load_lds( \
        (const __attribute__((address_space(1))) unsigned int*)(gp), \
        (__attribute__((address_space(3))) unsigned int*)(lp), 16, 0, 0)

// ---------------- shared transpose body (f32 [K][N] -> bf16 [N][K]) --------
__device__ __forceinline__ void transpose_body(
    const float* __restrict__ in, ushort* __restrict__ out,
    int K, int N, int bK, int bN, int tid, float (*tile)[33])
{
    const int k0 = bK * 32, n0 = bN * 32;
    const int tx = tid & 31, ty = tid >> 5;
#pragma unroll
    for (int i = ty; i < 32; i += 8)
        tile[i][tx] = in[(size_t)(k0 + i) * N + n0 + tx];
    __syncthreads();
#pragma unroll
    for (int i = ty; i < 32; i += 8)
        out[(size_t)(n0 + i) * K + k0 + tx] = f2bf(tile[tx][i]);
}

// ---------------- fused prologue: ALL transposes + bias concats + rmsnorm1 --
__global__ __launch_bounds__(256) void prep_kernel(
    const float* __restrict__ x, const float* __restrict__ g1,
    const float* __restrict__ Wq, const float* __restrict__ Wdown,
    const float* __restrict__ Wk, const float* __restrict__ Wv,
    const float* __restrict__ Wo, const float* __restrict__ W1,
    const float* __restrict__ W2,
    const float* __restrict__ bq, const float* __restrict__ bdown,
    const float* __restrict__ bk, const float* __restrict__ bv,
    ushort* __restrict__ WqdT, ushort* __restrict__ WkvT,
    ushort* __restrict__ WoT, ushort* __restrict__ W1T,
    ushort* __restrict__ W2T,
    float* __restrict__ bkv, float* __restrict__ bqd,
    ushort* __restrict__ hbuf)
{
    __shared__ float tile[32][33];
    __shared__ float sums[4];
    int b = blockIdx.x;
    const int tid = threadIdx.x;
    if (b < 1024) {
        transpose_body(Wq, WqdT, TD, TH, b & 31, b >> 5, tid, tile);
    } else if (b < 1280) {
        b -= 1024;
        transpose_body(Wdown, WqdT + (size_t)TH * TD, TD, TL, b & 31, b >> 5, tid, tile);
    } else if (b < 1536) {
        b -= 1280;
        transpose_body(Wk, WkvT, TL, TH, b & 7, b >> 3, tid, tile);
    } else if (b < 1792) {
        b -= 1536;
        transpose_body(Wv, WkvT + (size_t)TH * TL, TL, TH, b & 7, b >> 3, tid, tile);
    } else if (b < 2816) {
        b -= 1792;
        transpose_body(Wo, WoT, TH, TD, b & 31, b >> 5, tid, tile);
    } else if (b < 6912) {
        b -= 2816;
        transpose_body(W1, W1T, TD, TDF, b & 31, b >> 5, tid, tile);
    } else if (b < 11008) {
        b -= 6912;
        transpose_body(W2, W2T, TDF, TD, b & 127, b >> 7, tid, tile);
    } else if (b < 11016) {
        b -= 11008;
        const int i = b * 256 + tid;
        bkv[i] = (i < TH) ? bk[i] : bv[i - TH];
    } else if (b < 11021) {
        b -= 11016;
        const int i = b * 256 + tid;
        if (i < TQC) bqd[i] = (i < TH) ? bq[i] : bdown[i - TH];
    } else {
        const int row = b - 11021;
        const float4 v = ((const float4*)(x + (size_t)row * TD))[tid];
        float ss = v.x * v.x + v.y * v.y + v.z * v.z + v.w * v.w;
#pragma unroll
        for (int off = 32; off > 0; off >>= 1) ss += __shfl_down(ss, off);
        if ((tid & 63) == 0) sums[tid >> 6] = ss;
        __syncthreads();
        const float tot = sums[0] + sums[1] + sums[2] + sums[3];
        const float scale = rsqrtf(tot / (float)TD + 1e-6f);
        const float4 gv = ((const float4*)g1)[tid];
        ushort4 o;
        o.x = f2bf(v.x * scale * gv.x);
        o.y = f2bf(v.y * scale * gv.y);
        o.z = f2bf(v.z * scale * gv.z);
        o.w = f2bf(v.w * scale * gv.w);
        *(ushort4*)(hbuf + (size_t)row * TD + tid * 4) = o;
    }
}

// ---------------- RMSNorm: f32 in -> bf16 out (second norm) ----------------
__global__ __launch_bounds__(256) void rmsnorm_kernel(
    const float* __restrict__ x, const float* __restrict__ g,
    ushort* __restrict__ out, int D)
{
    const int row = blockIdx.x;
    const int tid = threadIdx.x;
    const float4 v = ((const float4*)(x + (size_t)row * D))[tid];
    float ss = v.x * v.x + v.y * v.y + v.z * v.z + v.w * v.w;
#pragma unroll
    for (int off = 32; off > 0; off >>= 1) ss += __shfl_down(ss, off);
    __shared__ float sums[4];
    if ((tid & 63) == 0) sums[tid >> 6] = ss;
    __syncthreads();
    const float tot = sums[0] + sums[1] + sums[2] + sums[3];
    const float scale = rsqrtf(tot / (float)D + 1e-6f);
    const float4 gv = ((const float4*)g)[tid];
    ushort4 o;
    o.x = f2bf(v.x * scale * gv.x);
    o.y = f2bf(v.y * scale * gv.y);
    o.z = f2bf(v.z * scale * gv.z);
    o.w = f2bf(v.w * scale * gv.w);
    *(ushort4*)(out + (size_t)row * D + tid * 4) = o;
}

// ---------------- bf16 GEMM (2-phase): C = A @ BT^T + bias, epilogue --------
template <int EPI, int BM, int BN, int BKH, int NKS>
__global__ __launch_bounds__(256) void gemm_bf16_kernel(
    const ushort* __restrict__ A, const ushort* __restrict__ BT,
    const float* __restrict__ bias, const float* __restrict__ resid,
    void* __restrict__ outp, int M, int N, int K, int lda)
{
    constexpr int WM = BM / 2, WN = BN / 2;
    constexpr int MT = WM / 16, NT = WN / 16;
    constexpr int NLA = BM / 64, NLB = BN / 64;
    __shared__ alignas(16) ushort As[2][BKH][BM * 32];
    __shared__ alignas(16) ushort Bs[2][BKH][BN * 32];
    const int bm = blockIdx.y * BM, bn = blockIdx.x * BN;
    const int tid = threadIdx.x;
    const int lane = tid & 63, wave = tid >> 6;
    const int wr = (wave >> 1) * WM, wc = (wave & 1) * WN;
    const int l15 = lane & 15, l4 = lane >> 4;

    const int Kblk = K / NKS;
    const int kbeg = (NKS > 1) ? (int)blockIdx.z * Kblk : 0;

    f32x4 acc[MT][NT] = {};

    const int grow = wave * 16 + (lane >> 2);
    const int gcol = (lane & 3) * 8;
    const ushort* Ag = A + (size_t)(bm + grow) * lda + gcol + kbeg;
    const ushort* Bg = BT + (size_t)(bn + grow) * K + gcol + kbeg;

    auto stage = [&](int buf, int k0) {
#pragma unroll
        for (int h = 0; h < BKH; ++h) {
#pragma unroll
            for (int i = 0; i < NLA; ++i)
                GLD_LDS(Ag + (size_t)(i * 64) * lda + k0 + h * 32,
                        &As[buf][h][(i * 64 + wave * 16) * 32]);
#pragma unroll
            for (int i = 0; i < NLB; ++i)
                GLD_LDS(Bg + (size_t)(i * 64) * K + k0 + h * 32,
                        &Bs[buf][h][(i * 64 + wave * 16) * 32]);
        }
    };

    stage(0, 0);
    asm volatile("s_waitcnt vmcnt(0)" ::: "memory");
    __syncthreads();

    const int nsteps = Kblk / (32 * BKH);
    for (int t = 0; t < nsteps; ++t) {
        const int cur = t & 1;
        if (t + 1 < nsteps) stage(cur ^ 1, (t + 1) * 32 * BKH);

#pragma unroll
        for (int h = 0; h < BKH; ++h) {
            bf16x8 af[MT], bf[NT];
#pragma unroll
            for (int mt = 0; mt < MT; ++mt)
                af[mt] = *(const bf16x8*)&As[cur][h][(wr + mt * 16 + l15) * 32 + l4 * 8];
#pragma unroll
            for (int nt = 0; nt < NT; ++nt)
                bf[nt] = *(const bf16x8*)&Bs[cur][h][(wc + nt * 16 + l15) * 32 + l4 * 8];
#pragma unroll
            for (int mt = 0; mt < MT; ++mt)
#pragma unroll
                for (int nt = 0; nt < NT; ++nt)
                    acc[mt][nt] = __builtin_amdgcn_mfma_f32_16x16x32_bf16(
                        af[mt], bf[nt], acc[mt][nt], 0, 0, 0);
        }

        asm volatile("s_waitcnt vmcnt(0)" ::: "memory");
        __syncthreads();
    }

#pragma unroll
    for (int mt = 0; mt < MT; ++mt) {
#pragma unroll
        for (int nt = 0; nt < NT; ++nt) {
#pragma unroll
            for (int i = 0; i < 4; ++i) {
                const int row = bm + wr + mt * 16 + l4 * 4 + i;
                const int col = bn + wc + nt * 16 + l15;
                float v = acc[mt][nt][i];
                if constexpr (EPI != 4) v += bias[col];
                if constexpr (EPI == 1 || EPI == 3) v = v / (1.f + __expf(-v));  // silu
                if constexpr (EPI == 2 || EPI == 3) v += resid[(size_t)row * N + col];
                if constexpr (EPI == 0 || EPI == 1)
                    ((ushort*)outp)[(size_t)row * N + col] = f2bf(v);
                else if constexpr (EPI == 4)
                    ((float*)outp)[(size_t)blockIdx.z * M * N + (size_t)row * N + col] = v;
                else
                    ((float*)outp)[(size_t)row * N + col] = v;
            }
        }
    }
}

// ---------------- W2 split-K combine: out = silu(p0+p1+bias) + resid --------
__global__ __launch_bounds__(256) void w2_combine_kernel(
    const float* __restrict__ P, const float* __restrict__ bias,
    const float* __restrict__ resid, float* __restrict__ out)
{
    const int idx = blockIdx.x * 256 + threadIdx.x;   // one float4
    const int c4 = idx & (TD / 4 - 1);
    const float4 p0 = ((const float4*)P)[idx];
    const float4 p1 = ((const float4*)(P + (size_t)TS * TD))[idx];
    const float4 bb = ((const float4*)bias)[c4];
    const float4 rr = ((const float4*)resid)[idx];
    float4 o;
    float v;
    v = p0.x + p1.x + bb.x; o.x = v / (1.f + __expf(-v)) + rr.x;
    v = p0.y + p1.y + bb.y; o.y = v / (1.f + __expf(-v)) + rr.y;
    v = p0.z + p1.z + bb.z; o.z = v / (1.f + __expf(-v)) + rr.z;
    v = p0.w + p1.w + bb.w; o.w = v / (1.f + __expf(-v)) + rr.w;
    ((float4*)out)[idx] = o;
}

// ---------------- causal flash attention (MLA), 8-wave QBLK=128, split-KV x8 -
// grid (S/128, NH, NSPLIT=8); block 512 = 8 waves. Single-buffered K/V LDS
// (32 KB -> 4 blk/CU). Finer split: max chunk 4 iters -> uniform blocks,
// shorter drain tail. Split ranges disjoint -> no extra KV fetch.
__global__ __launch_bounds__(512) void mla_attn_kernel(
    const ushort* __restrict__ Q, const ushort* __restrict__ Kg,
    const ushort* __restrict__ Vg, ushort* __restrict__ OP, float* __restrict__ ML)
{
    constexpr int QSTR = TQC, KSTR = 2048;
    __shared__ alignas(16) ushort Ks[64 * 64];    // [key][d], lo-swz
    __shared__ alignas(16) ushort VTs[64 * 64];   // [d][key], hi-swz
    __shared__ alignas(16) ushort Ps[8][16 * 64]; // per-wave [q][key], lo-swz
    const int qb = (int)gridDim.x - 1 - (int)blockIdx.x;   // heavy blocks first
    const int h = blockIdx.y;
    const int sp = blockIdx.z;
    const int tid = threadIdx.x, lane = tid & 63, wave = tid >> 6;
    const int l15 = lane & 15, l4 = lane >> 4;
    const int qrow0 = qb * 128 + wave * 16;
    const int myq = qrow0 + l15;

    const int ntile = 2 * (qb + 1);
    const int chunk = (ntile + NSPLIT - 1) / NSPLIT;
    const int kt0 = sp * chunk;
    const int ktend = min(ntile, kt0 + chunk);

    auto swzK = [](ushort* base, int row, int colbyte) -> ushort* {
        return (ushort*)((char*)base + row * 128 + (colbyte ^ ((row & 7) << 4)));
    };
    auto swzVT = [](ushort* base, int d, int colbyte) -> ushort* {
        return (ushort*)((char*)base + d * 128 + (colbyte ^ (((d >> 3) & 7) << 4)));
    };
    auto swzP = [&](int row, int colbyte) -> ushort* {
        return (ushort*)((char*)&Ps[wave][0] + row * 128 + (colbyte ^ ((row & 7) << 4)));
    };

    f32x4 oacc[4] = {};          // oacc[dt][i] = o[d = dt*16 + l4*4 + i][q = myq]
    float m_run = -1e30f, l_run = 0.f;   // raw-score domain

    // staging: 512 threads cover 64 rows x 64 cols, ONE uint4 per matrix each
    const int sr = tid >> 3, sc = (tid & 7) * 8;
    const ushort* kbase = Kg + (size_t)sr * KSTR + h * THD + sc;
    const ushort* vbase = Vg + (size_t)sr * KSTR + h * THD + sc;

    if (kt0 < ktend) {
        bf16x8 qf[2];
#pragma unroll
        for (int ks = 0; ks < 2; ++ks)
            qf[ks] = *(const bf16x8*)&Q[(size_t)myq * QSTR + h * THD + ks * 32 + l4 * 8];

        uint4 kr0, vr0;
        {   // prefetch first tile into regs
            const size_t off = (size_t)kt0 * 64 * KSTR;
            kr0 = *(const uint4*)(kbase + off);
            vr0 = *(const uint4*)(vbase + off);
        }

        for (int kt = kt0; kt < ktend; ++kt) {
            __syncthreads();   // all waves done reading Ks/VTs of previous tile
            *(uint4*)swzK(Ks, sr, sc * 2) = kr0;
            {
                const ushort* p0 = (const ushort*)&vr0;
#pragma unroll
                for (int j = 0; j < 8; ++j)
                    *swzVT(VTs, sc + j, sr * 2) = p0[j];
            }
            __syncthreads();   // tile kt visible
            if (kt + 1 < ktend) {   // prefetch next tile
                const size_t off = (size_t)(kt + 1) * 64 * KSTR;
                kr0 = *(const uint4*)(kbase + off);
                vr0 = *(const uint4*)(vbase + off);
            }

            // ---- scores SWAPPED: s[nt][i] = rawscore[key][q=l15] ----
            f32x4 s[4] = {};
            __builtin_amdgcn_s_setprio(1);
#pragma unroll
            for (int ks = 0; ks < 2; ++ks) {
#pragma unroll
                for (int nt = 0; nt < 4; ++nt) {
                    const bf16x8 kf = *(const bf16x8*)swzK(Ks, nt * 16 + l15, ks * 64 + l4 * 16);
                    s[nt] = __builtin_amdgcn_mfma_f32_16x16x32_bf16(kf, qf[ks], s[nt], 0, 0, 0);
                }
            }
            __builtin_amdgcn_s_setprio(0);

            // ---- causal mask: only the diagonal-region tiles (last two) ----
            if (kt >= 2 * qb) {
                const int kb = kt * 64;
#pragma unroll
                for (int nt = 0; nt < 4; ++nt)
#pragma unroll
                    for (int i = 0; i < 4; ++i)
                        if (kb + nt * 16 + l4 * 4 + i > myq) s[nt][i] = -3.0e38f;
            }

            // ---- per-lane softmax (raw domain; exp2 with folded scale) ----
            float mx = m_run;
#pragma unroll
            for (int nt = 0; nt < 4; ++nt)
#pragma unroll
                for (int i = 0; i < 4; ++i) mx = fmaxf(mx, s[nt][i]);
            mx = fmaxf(mx, __shfl_xor(mx, 16));
            mx = fmaxf(mx, __shfl_xor(mx, 32));
            const float alpha = exp2f((m_run - mx) * ATT_CE);
            m_run = mx;
            float ps = 0.f;
#pragma unroll
            for (int nt = 0; nt < 4; ++nt)
#pragma unroll
                for (int i = 0; i < 4; ++i) {
                    const float p = exp2f((s[nt][i] - mx) * ATT_CE);
                    s[nt][i] = p;
                    ps += p;
                }
            ps += __shfl_xor(ps, 16);
            ps += __shfl_xor(ps, 32);
            l_run = l_run * alpha + ps;

#pragma unroll
            for (int dt = 0; dt < 4; ++dt)
#pragma unroll
                for (int i = 0; i < 4; ++i) oacc[dt][i] *= alpha;

            // ---- P -> LDS [q=l15][key], packed 4 keys per store ----
#pragma unroll
            for (int nt = 0; nt < 4; ++nt) {
                ushort4 pk;
                pk.x = f2bf_hw(s[nt][0]); pk.y = f2bf_hw(s[nt][1]);
                pk.z = f2bf_hw(s[nt][2]); pk.w = f2bf_hw(s[nt][3]);
                *(ushort4*)swzP(l15, nt * 32 + l4 * 8) = pk;
            }

            // ---- PV SWAPPED: oacc[dt] += mfma(V^T, P) -> o[d][q=l15] ----
            __builtin_amdgcn_s_setprio(1);
#pragma unroll
            for (int ks = 0; ks < 2; ++ks) {
                const bf16x8 pf = *(const bf16x8*)swzP(l15, ks * 64 + l4 * 16);
#pragma unroll
                for (int dt = 0; dt < 4; ++dt) {
                    const bf16x8 vf = *(const bf16x8*)swzVT(VTs, dt * 16 + l15, ks * 64 + l4 * 16);
                    oacc[dt] = __builtin_amdgcn_mfma_f32_16x16x32_bf16(vf, pf, oacc[dt], 0, 0, 0);
                }
            }
            __builtin_amdgcn_s_setprio(0);
        }
    }

    // ---- epilogue: bf16 unnormalized partial + (m,l) (zeros if empty split) --
    ushort* op = OP + (size_t)sp * TS * TH;
#pragma unroll
    for (int dt = 0; dt < 4; ++dt) {
        ushort4 o4;
        o4.x = f2bf_hw(oacc[dt][0]); o4.y = f2bf_hw(oacc[dt][1]);
        o4.z = f2bf_hw(oacc[dt][2]); o4.w = f2bf_hw(oacc[dt][3]);
        *(ushort4*)&op[(size_t)myq * TH + h * THD + dt * 16 + l4 * 4] = o4;
    }
    if (l4 == 0) {   // lanes sharing l15 hold identical (m,l) after the reduces
        float* ml = ML + (size_t)sp * TS * TNH * 2;
        ml[((size_t)myq * TNH + h) * 2 + 0] = m_run;
        ml[((size_t)myq * TNH + h) * 2 + 1] = l_run;
    }
}

// ---------------- flash combine of NSPLIT KV-split partials ----------------
__global__ __launch_bounds__(256) void attn_combine_kernel(
    const ushort* __restrict__ OP, const float* __restrict__ ML,
    ushort* __restrict__ O)
{
    const int idx = blockIdx.x * 256 + threadIdx.x;   // one ushort4 of one row
    const int row = idx >> 8;                         // 256 x 4 elems per row
    const int h = (idx & 255) >> 4;
    float m[NSPLIT], l[NSPLIT];
#pragma unroll
    for (int sp = 0; sp < NSPLIT; ++sp) {
        m[sp] = ML[((size_t)sp * TS * TNH + (size_t)row * TNH + h) * 2 + 0];
        l[sp] = ML[((size_t)sp * TS * TNH + (size_t)row * TNH + h) * 2 + 1];
    }
    float M = m[0];
#pragma unroll
    for (int sp = 1; sp < NSPLIT; ++sp) M = fmaxf(M, m[sp]);
    float w[NSPLIT], den = 0.f;
#pragma unroll
    for (int sp = 0; sp < NSPLIT; ++sp) {
        w[sp] = exp2f((m[sp] - M) * ATT_CE);
        den += l[sp] * w[sp];
    }
    const float inv = 1.f / den;
    float ax = 0.f, ay = 0.f, az = 0.f, aw = 0.f;
#pragma unroll
    for (int sp = 0; sp < NSPLIT; ++sp) {
        const ushort4 u = ((const ushort4*)(OP + (size_t)sp * TS * TH))[idx];
        ax += w[sp] * bf2f(u.x);
        ay += w[sp] * bf2f(u.y);
        az += w[sp] * bf2f(u.z);
        aw += w[sp] * bf2f(u.w);
    }
    ushort4 o;
    o.x = f2bf_hw(ax * inv);
    o.y = f2bf_hw(ay * inv);
    o.z = f2bf_hw(az * inv);
    o.w = f2bf_hw(aw * inv);
    ((ushort4*)O)[idx] = o;
}

// ---------------- launch ----------------
extern "C" void kernel_launch(void* const* d_in, const int* in_sizes, int n_in,
                              void* d_out, int out_size, void* d_ws, size_t ws_size,
                              hipStream_t stream)
{
    const float* x     = (const float*)d_in[0];
    const float* g1    = (const float*)d_in[1];
    const float* Wq    = (const float*)d_in[2];
    const float* bq    = (const float*)d_in[3];
    const float* Wdown = (const float*)d_in[4];
    const float* bdown = (const float*)d_in[5];
    const float* Wk    = (const float*)d_in[6];
    const float* bk    = (const float*)d_in[7];
    const float* Wv    = (const float*)d_in[8];
    const float* bv    = (const float*)d_in[9];
    const float* Wo    = (const float*)d_in[10];
    const float* bo    = (const float*)d_in[11];
    const float* g2    = (const float*)d_in[12];
    const float* W1    = (const float*)d_in[13];
    const float* b1    = (const float*)d_in[14];
    const float* W2    = (const float*)d_in[15];
    const float* b2    = (const float*)d_in[16];
    float* out = (float*)d_out;

    char* ws = (char*)d_ws;
    size_t off = 0;
    auto alloc = [&](size_t bytes) {
        void* p = ws + off;
        off += (bytes + 255) & ~(size_t)255;
        return p;
    };
    ushort* WqdT   = (ushort*)alloc((size_t)TQC * TD * 2);     // [1280][1024]
    ushort* WkvT   = (ushort*)alloc((size_t)2 * TH * TL * 2);  // [2048][256]
    ushort* WoT    = (ushort*)alloc((size_t)TD * TH * 2);
    ushort* W1T    = (ushort*)alloc((size_t)TDF * TD * 2);
    ushort* W2T    = (ushort*)alloc((size_t)TD * TDF * 2);
    float*  bkv    = (float*)alloc((size_t)2 * TH * 4);
    float*  bqd    = (float*)alloc((size_t)TQC * 4);
    ushort* hbuf   = (ushort*)alloc((size_t)TS * TD * 2);
    ushort* qcbuf  = (ushort*)alloc((size_t)TS * TQC * 2);     // [S][1280] = q|c
    ushort* kvbuf  = (ushort*)alloc((size_t)TS * 2 * TH * 2);  // [S][2048]
    ushort* obuf   = (ushort*)alloc((size_t)TS * TH * 2);
    float*  strm   = (float*)alloc((size_t)TS * TD * 4);
    ushort* h2buf  = (ushort*)alloc((size_t)TS * TD * 2);
    // ffn1 (16 MB) and psum (16 MB) allocated ADJACENT so the 8 bf16
    // O-partials (8 x 4 MB = 32 MB) can alias both (dead until W1/W2).
    ushort* ffn1   = (ushort*)alloc((size_t)TS * TDF * 2);     // 16 MB
    float*  psum   = (float*)alloc((size_t)2 * TS * TD * 4);   // 16 MB
    float*  mlbuf  = (float*)alloc((size_t)NSPLIT * TS * TNH * 2 * 4);
    ushort* opart  = (ushort*)ffn1;   // spans ffn1 + psum (32 MB)

    // fused prologue: ALL transposes + bias concats + rmsnorm1, one dispatch
    prep_kernel<<<13069, 256, 0, stream>>>(
        x, g1, Wq, Wdown, Wk, Wv, Wo, W1, W2, bq, bdown, bk, bv,
        WqdT, WkvT, WoT, W1T, W2T, bkv, bqd, hbuf);

    // fused Wq|Wdown GEMM -> qcbuf [S][1280]
    gemm_bf16_kernel<0, 64, 64, 2, 1><<<dim3(TQC / 64, TS / 64), 256, 0, stream>>>(
        hbuf, WqdT, bqd, nullptr, qcbuf, TS, TQC, TD, TD);
    // Wk|Wv GEMM: A = c columns of qcbuf (stride 1280)
    gemm_bf16_kernel<0, 64, 64, 2, 1><<<dim3(2 * TH / 64, TS / 64), 256, 0, stream>>>(
        qcbuf + TH, WkvT, bkv, nullptr, kvbuf, TS, 2 * TH, TL, TQC);

    // attn: 8-wave QBLK=128 blocks, single-buffered K/V, split-KV x8
    mla_attn_kernel<<<dim3(TS / 128, TNH, NSPLIT), 512, 0, stream>>>(
        qcbuf, kvbuf, kvbuf + TH, opart, mlbuf);
    attn_combine_kernel<<<(TS * TH / 4) / 256, 256, 0, stream>>>(
        opart, mlbuf, obuf);

    gemm_bf16_kernel<2, 64, 64, 2, 1><<<dim3(TD / 64, TS / 64), 256, 0, stream>>>(
        obuf, WoT, bo, x, strm, TS, TD, TH, TH);

    rmsnorm_kernel<<<TS, 256, 0, stream>>>(strm, g2, h2buf, TD);

    // W1: 128x64 tile (1024 blocks = 4/CU)
    gemm_bf16_kernel<1, 128, 64, 1, 1><<<dim3(TDF / 64, TS / 128), 256, 0, stream>>>(
        h2buf, W1T, b1, nullptr, ffn1, TS, TDF, TD, TD);

    // W2 split-K x2 -> f32 partials, then fused bias+silu+resid combine
    gemm_bf16_kernel<4, 64, 64, 2, 2><<<dim3(TD / 64, TS / 64, 2), 256, 0, stream>>>(
        ffn1, W2T, nullptr, nullptr, psum, TS, TD, TDF, TDF);
    w2_combine_kernel<<<(TS * TD / 4) / 256, 256, 0, stream>>>(
        psum, b2, strm, out);
}

// Round 20
// 179.815 us; speedup vs baseline: 1.0325x; 1.0325x over previous
//
#include <hip/hip_runtime.h>

// ---------------- types ----------------
typedef __bf16 bf16x8 __attribute__((ext_vector_type(8)));
typedef float  f32x4  __attribute__((ext_vector_type(4)));

static __device__ __forceinline__ ushort f2bf(float f) {
    union { float f; unsigned u; } a; a.f = f;
    unsigned r = a.u + 0x7FFFu + ((a.u >> 16) & 1u);   // RNE
    return (ushort)(r >> 16);
}
static __device__ __forceinline__ ushort f2bf_hw(float f) {
    __bf16 b = (__bf16)f;                               // HW cvt (RNE), pairs -> cvt_pk
    return __builtin_bit_cast(ushort, b);
}
static __device__ __forceinline__ float bf2f(ushort u) {
    return __builtin_bit_cast(float, (unsigned)u << 16);
}

// ---------------- constants ----------------
#define TS  2048   // S
#define TD  1024   // D
#define TL  256    // L
#define TH  1024   // H
#define TNH 16
#define THD 64
#define TDF 4096   // 4*D
#define TQC 1280   // fused q|c output width (H + L)
#define ATT_CE 0.18033688f   // 0.125 * log2(e)
#define NSPLIT 4   // measured optimum: 8 regressed (per-split fixed costs), r19

#define GLD_LDS(gp, lp) \
    __builtin_amdgcn_global_load_lds( \
        (const __attribute__((address_space(1))) unsigned int*)(gp), \
        (__attribute__((address_space(3))) unsigned int*)(lp), 16, 0, 0)

// ---------------- shared transpose body (f32 [K][N] -> bf16 [N][K]) --------
__device__ __forceinline__ void transpose_body(
    const float* __restrict__ in, ushort* __restrict__ out,
    int K, int N, int bK, int bN, int tid, float (*tile)[33])
{
    const int k0 = bK * 32, n0 = bN * 32;
    const int tx = tid & 31, ty = tid >> 5;
#pragma unroll
    for (int i = ty; i < 32; i += 8)
        tile[i][tx] = in[(size_t)(k0 + i) * N + n0 + tx];
    __syncthreads();
#pragma unroll
    for (int i = ty; i < 32; i += 8)
        out[(size_t)(n0 + i) * K + k0 + tx] = f2bf(tile[tx][i]);
}

// ---------------- fused prologue: ALL transposes + bias concats + rmsnorm1 --
__global__ __launch_bounds__(256) void prep_kernel(
    const float* __restrict__ x, const float* __restrict__ g1,
    const float* __restrict__ Wq, const float* __restrict__ Wdown,
    const float* __restrict__ Wk, const float* __restrict__ Wv,
    const float* __restrict__ Wo, const float* __restrict__ W1,
    const float* __restrict__ W2,
    const float* __restrict__ bq, const float* __restrict__ bdown,
    const float* __restrict__ bk, const float* __restrict__ bv,
    ushort* __restrict__ WqdT, ushort* __restrict__ WkvT,
    ushort* __restrict__ WoT, ushort* __restrict__ W1T,
    ushort* __restrict__ W2T,
    float* __restrict__ bkv, float* __restrict__ bqd,
    ushort* __restrict__ hbuf)
{
    __shared__ float tile[32][33];
    __shared__ float sums[4];
    int b = blockIdx.x;
    const int tid = threadIdx.x;
    if (b < 1024) {
        transpose_body(Wq, WqdT, TD, TH, b & 31, b >> 5, tid, tile);
    } else if (b < 1280) {
        b -= 1024;
        transpose_body(Wdown, WqdT + (size_t)TH * TD, TD, TL, b & 31, b >> 5, tid, tile);
    } else if (b < 1536) {
        b -= 1280;
        transpose_body(Wk, WkvT, TL, TH, b & 7, b >> 3, tid, tile);
    } else if (b < 1792) {
        b -= 1536;
        transpose_body(Wv, WkvT + (size_t)TH * TL, TL, TH, b & 7, b >> 3, tid, tile);
    } else if (b < 2816) {
        b -= 1792;
        transpose_body(Wo, WoT, TH, TD, b & 31, b >> 5, tid, tile);
    } else if (b < 6912) {
        b -= 2816;
        transpose_body(W1, W1T, TD, TDF, b & 31, b >> 5, tid, tile);
    } else if (b < 11008) {
        b -= 6912;
        transpose_body(W2, W2T, TDF, TD, b & 127, b >> 7, tid, tile);
    } else if (b < 11016) {
        b -= 11008;
        const int i = b * 256 + tid;
        bkv[i] = (i < TH) ? bk[i] : bv[i - TH];
    } else if (b < 11021) {
        b -= 11016;
        const int i = b * 256 + tid;
        if (i < TQC) bqd[i] = (i < TH) ? bq[i] : bdown[i - TH];
    } else {
        const int row = b - 11021;
        const float4 v = ((const float4*)(x + (size_t)row * TD))[tid];
        float ss = v.x * v.x + v.y * v.y + v.z * v.z + v.w * v.w;
#pragma unroll
        for (int off = 32; off > 0; off >>= 1) ss += __shfl_down(ss, off);
        if ((tid & 63) == 0) sums[tid >> 6] = ss;
        __syncthreads();
        const float tot = sums[0] + sums[1] + sums[2] + sums[3];
        const float scale = rsqrtf(tot / (float)TD + 1e-6f);
        const float4 gv = ((const float4*)g1)[tid];
        ushort4 o;
        o.x = f2bf(v.x * scale * gv.x);
        o.y = f2bf(v.y * scale * gv.y);
        o.z = f2bf(v.z * scale * gv.z);
        o.w = f2bf(v.w * scale * gv.w);
        *(ushort4*)(hbuf + (size_t)row * TD + tid * 4) = o;
    }
}

// ---------------- RMSNorm: f32 in -> bf16 out (second norm) ----------------
__global__ __launch_bounds__(256) void rmsnorm_kernel(
    const float* __restrict__ x, const float* __restrict__ g,
    ushort* __restrict__ out, int D)
{
    const int row = blockIdx.x;
    const int tid = threadIdx.x;
    const float4 v = ((const float4*)(x + (size_t)row * D))[tid];
    float ss = v.x * v.x + v.y * v.y + v.z * v.z + v.w * v.w;
#pragma unroll
    for (int off = 32; off > 0; off >>= 1) ss += __shfl_down(ss, off);
    __shared__ float sums[4];
    if ((tid & 63) == 0) sums[tid >> 6] = ss;
    __syncthreads();
    const float tot = sums[0] + sums[1] + sums[2] + sums[3];
    const float scale = rsqrtf(tot / (float)D + 1e-6f);
    const float4 gv = ((const float4*)g)[tid];
    ushort4 o;
    o.x = f2bf(v.x * scale * gv.x);
    o.y = f2bf(v.y * scale * gv.y);
    o.z = f2bf(v.z * scale * gv.z);
    o.w = f2bf(v.w * scale * gv.w);
    *(ushort4*)(out + (size_t)row * D + tid * 4) = o;
}

// ---------------- bf16 GEMM (2-phase): C = A @ BT^T + bias, epilogue --------
template <int EPI, int BM, int BN, int BKH, int NKS>
__global__ __launch_bounds__(256) void gemm_bf16_kernel(
    const ushort* __restrict__ A, const ushort* __restrict__ BT,
    const float* __restrict__ bias, const float* __restrict__ resid,
    void* __restrict__ outp, int M, int N, int K, int lda)
{
    constexpr int WM = BM / 2, WN = BN / 2;
    constexpr int MT = WM / 16, NT = WN / 16;
    constexpr int NLA = BM / 64, NLB = BN / 64;
    __shared__ alignas(16) ushort As[2][BKH][BM * 32];
    __shared__ alignas(16) ushort Bs[2][BKH][BN * 32];
    const int bm = blockIdx.y * BM, bn = blockIdx.x * BN;
    const int tid = threadIdx.x;
    const int lane = tid & 63, wave = tid >> 6;
    const int wr = (wave >> 1) * WM, wc = (wave & 1) * WN;
    const int l15 = lane & 15, l4 = lane >> 4;

    const int Kblk = K / NKS;
    const int kbeg = (NKS > 1) ? (int)blockIdx.z * Kblk : 0;

    f32x4 acc[MT][NT] = {};

    const int grow = wave * 16 + (lane >> 2);
    const int gcol = (lane & 3) * 8;
    const ushort* Ag = A + (size_t)(bm + grow) * lda + gcol + kbeg;
    const ushort* Bg = BT + (size_t)(bn + grow) * K + gcol + kbeg;

    auto stage = [&](int buf, int k0) {
#pragma unroll
        for (int h = 0; h < BKH; ++h) {
#pragma unroll
            for (int i = 0; i < NLA; ++i)
                GLD_LDS(Ag + (size_t)(i * 64) * lda + k0 + h * 32,
                        &As[buf][h][(i * 64 + wave * 16) * 32]);
#pragma unroll
            for (int i = 0; i < NLB; ++i)
                GLD_LDS(Bg + (size_t)(i * 64) * K + k0 + h * 32,
                        &Bs[buf][h][(i * 64 + wave * 16) * 32]);
        }
    };

    stage(0, 0);
    asm volatile("s_waitcnt vmcnt(0)" ::: "memory");
    __syncthreads();

    const int nsteps = Kblk / (32 * BKH);
    for (int t = 0; t < nsteps; ++t) {
        const int cur = t & 1;
        if (t + 1 < nsteps) stage(cur ^ 1, (t + 1) * 32 * BKH);

#pragma unroll
        for (int h = 0; h < BKH; ++h) {
            bf16x8 af[MT], bf[NT];
#pragma unroll
            for (int mt = 0; mt < MT; ++mt)
                af[mt] = *(const bf16x8*)&As[cur][h][(wr + mt * 16 + l15) * 32 + l4 * 8];
#pragma unroll
            for (int nt = 0; nt < NT; ++nt)
                bf[nt] = *(const bf16x8*)&Bs[cur][h][(wc + nt * 16 + l15) * 32 + l4 * 8];
#pragma unroll
            for (int mt = 0; mt < MT; ++mt)
#pragma unroll
                for (int nt = 0; nt < NT; ++nt)
                    acc[mt][nt] = __builtin_amdgcn_mfma_f32_16x16x32_bf16(
                        af[mt], bf[nt], acc[mt][nt], 0, 0, 0);
        }

        asm volatile("s_waitcnt vmcnt(0)" ::: "memory");
        __syncthreads();
    }

#pragma unroll
    for (int mt = 0; mt < MT; ++mt) {
#pragma unroll
        for (int nt = 0; nt < NT; ++nt) {
#pragma unroll
            for (int i = 0; i < 4; ++i) {
                const int row = bm + wr + mt * 16 + l4 * 4 + i;
                const int col = bn + wc + nt * 16 + l15;
                float v = acc[mt][nt][i];
                if constexpr (EPI != 4) v += bias[col];
                if constexpr (EPI == 1 || EPI == 3) v = v / (1.f + __expf(-v));  // silu
                if constexpr (EPI == 2 || EPI == 3) v += resid[(size_t)row * N + col];
                if constexpr (EPI == 0 || EPI == 1)
                    ((ushort*)outp)[(size_t)row * N + col] = f2bf(v);
                else if constexpr (EPI == 4)
                    ((float*)outp)[(size_t)blockIdx.z * M * N + (size_t)row * N + col] = v;
                else
                    ((float*)outp)[(size_t)row * N + col] = v;
            }
        }
    }
}

// ---------------- W2 split-K combine: out = silu(p0+p1+bias) + resid --------
__global__ __launch_bounds__(256) void w2_combine_kernel(
    const float* __restrict__ P, const float* __restrict__ bias,
    const float* __restrict__ resid, float* __restrict__ out)
{
    const int idx = blockIdx.x * 256 + threadIdx.x;   // one float4
    const int c4 = idx & (TD / 4 - 1);
    const float4 p0 = ((const float4*)P)[idx];
    const float4 p1 = ((const float4*)(P + (size_t)TS * TD))[idx];
    const float4 bb = ((const float4*)bias)[c4];
    const float4 rr = ((const float4*)resid)[idx];
    float4 o;
    float v;
    v = p0.x + p1.x + bb.x; o.x = v / (1.f + __expf(-v)) + rr.x;
    v = p0.y + p1.y + bb.y; o.y = v / (1.f + __expf(-v)) + rr.y;
    v = p0.z + p1.z + bb.z; o.z = v / (1.f + __expf(-v)) + rr.z;
    v = p0.w + p1.w + bb.w; o.w = v / (1.f + __expf(-v)) + rr.w;
    ((float4*)out)[idx] = o;
}

// ---------------- causal flash attention (MLA), 8-wave QBLK=128, split-KV x4 -
// grid (S/128, NH, NSPLIT); block 512 = 8 waves. Single-buffered K/V LDS
// (32 KB -> 4 blk/CU = 32 waves/CU). Per iter: sync -> regs->LDS -> sync ->
// prefetch next tile into regs -> compute. (r18 measured optimum, 180.3us.)
__global__ __launch_bounds__(512) void mla_attn_kernel(
    const ushort* __restrict__ Q, const ushort* __restrict__ Kg,
    const ushort* __restrict__ Vg, ushort* __restrict__ OP, float* __restrict__ ML)
{
    constexpr int QSTR = TQC, KSTR = 2048;
    __shared__ alignas(16) ushort Ks[64 * 64];    // [key][d], lo-swz
    __shared__ alignas(16) ushort VTs[64 * 64];   // [d][key], hi-swz
    __shared__ alignas(16) ushort Ps[8][16 * 64]; // per-wave [q][key], lo-swz
    const int qb = (int)gridDim.x - 1 - (int)blockIdx.x;   // heavy blocks first
    const int h = blockIdx.y;
    const int sp = blockIdx.z;
    const int tid = threadIdx.x, lane = tid & 63, wave = tid >> 6;
    const int l15 = lane & 15, l4 = lane >> 4;
    const int qrow0 = qb * 128 + wave * 16;
    const int myq = qrow0 + l15;

    const int ntile = 2 * (qb + 1);
    const int chunk = (ntile + NSPLIT - 1) / NSPLIT;
    const int kt0 = sp * chunk;
    const int ktend = min(ntile, kt0 + chunk);

    auto swzK = [](ushort* base, int row, int colbyte) -> ushort* {
        return (ushort*)((char*)base + row * 128 + (colbyte ^ ((row & 7) << 4)));
    };
    auto swzVT = [](ushort* base, int d, int colbyte) -> ushort* {
        return (ushort*)((char*)base + d * 128 + (colbyte ^ (((d >> 3) & 7) << 4)));
    };
    auto swzP = [&](int row, int colbyte) -> ushort* {
        return (ushort*)((char*)&Ps[wave][0] + row * 128 + (colbyte ^ ((row & 7) << 4)));
    };

    bf16x8 qf[2];
#pragma unroll
    for (int ks = 0; ks < 2; ++ks)
        qf[ks] = *(const bf16x8*)&Q[(size_t)myq * QSTR + h * THD + ks * 32 + l4 * 8];

    f32x4 oacc[4] = {};          // oacc[dt][i] = o[d = dt*16 + l4*4 + i][q = myq]
    float m_run = -1e30f, l_run = 0.f;   // raw-score domain

    // staging: 512 threads cover 64 rows x 64 cols, ONE uint4 per matrix each
    const int sr = tid >> 3, sc = (tid & 7) * 8;
    const ushort* kbase = Kg + (size_t)sr * KSTR + h * THD + sc;
    const ushort* vbase = Vg + (size_t)sr * KSTR + h * THD + sc;

    uint4 kr0, vr0;
    if (kt0 < ktend) {   // prefetch first tile into regs
        const size_t off = (size_t)kt0 * 64 * KSTR;
        kr0 = *(const uint4*)(kbase + off);
        vr0 = *(const uint4*)(vbase + off);
    }

    for (int kt = kt0; kt < ktend; ++kt) {
        __syncthreads();   // all waves done reading Ks/VTs of previous tile
        *(uint4*)swzK(Ks, sr, sc * 2) = kr0;
        {
            const ushort* p0 = (const ushort*)&vr0;
#pragma unroll
            for (int j = 0; j < 8; ++j)
                *swzVT(VTs, sc + j, sr * 2) = p0[j];
        }
        __syncthreads();   // tile kt visible
        if (kt + 1 < ktend) {   // prefetch next tile (latency hides under compute)
            const size_t off = (size_t)(kt + 1) * 64 * KSTR;
            kr0 = *(const uint4*)(kbase + off);
            vr0 = *(const uint4*)(vbase + off);
        }

        // ---- scores SWAPPED: s[nt][i] = rawscore[key][q=l15] ----
        f32x4 s[4] = {};
        __builtin_amdgcn_s_setprio(1);
#pragma unroll
        for (int ks = 0; ks < 2; ++ks) {
#pragma unroll
            for (int nt = 0; nt < 4; ++nt) {
                const bf16x8 kf = *(const bf16x8*)swzK(Ks, nt * 16 + l15, ks * 64 + l4 * 16);
                s[nt] = __builtin_amdgcn_mfma_f32_16x16x32_bf16(kf, qf[ks], s[nt], 0, 0, 0);
            }
        }
        __builtin_amdgcn_s_setprio(0);

        // ---- causal mask: only the diagonal-region tiles (last two) ----
        if (kt >= 2 * qb) {
            const int kb = kt * 64;
#pragma unroll
            for (int nt = 0; nt < 4; ++nt)
#pragma unroll
                for (int i = 0; i < 4; ++i)
                    if (kb + nt * 16 + l4 * 4 + i > myq) s[nt][i] = -3.0e38f;
        }

        // ---- per-lane softmax (raw domain; exp2 with folded scale) ----
        float mx = m_run;
#pragma unroll
        for (int nt = 0; nt < 4; ++nt)
#pragma unroll
            for (int i = 0; i < 4; ++i) mx = fmaxf(mx, s[nt][i]);
        mx = fmaxf(mx, __shfl_xor(mx, 16));
        mx = fmaxf(mx, __shfl_xor(mx, 32));
        const float alpha = exp2f((m_run - mx) * ATT_CE);
        m_run = mx;
        float ps = 0.f;
#pragma unroll
        for (int nt = 0; nt < 4; ++nt)
#pragma unroll
            for (int i = 0; i < 4; ++i) {
                const float p = exp2f((s[nt][i] - mx) * ATT_CE);
                s[nt][i] = p;
                ps += p;
            }
        ps += __shfl_xor(ps, 16);
        ps += __shfl_xor(ps, 32);
        l_run = l_run * alpha + ps;

#pragma unroll
        for (int dt = 0; dt < 4; ++dt)
#pragma unroll
            for (int i = 0; i < 4; ++i) oacc[dt][i] *= alpha;

        // ---- P -> LDS [q=l15][key], packed 4 keys per store ----
#pragma unroll
        for (int nt = 0; nt < 4; ++nt) {
            ushort4 pk;
            pk.x = f2bf_hw(s[nt][0]); pk.y = f2bf_hw(s[nt][1]);
            pk.z = f2bf_hw(s[nt][2]); pk.w = f2bf_hw(s[nt][3]);
            *(ushort4*)swzP(l15, nt * 32 + l4 * 8) = pk;
        }

        // ---- PV SWAPPED: oacc[dt] += mfma(V^T-frag, P-frag) -> o[d][q=l15] ----
        __builtin_amdgcn_s_setprio(1);
#pragma unroll
        for (int ks = 0; ks < 2; ++ks) {
            const bf16x8 pf = *(const bf16x8*)swzP(l15, ks * 64 + l4 * 16);
#pragma unroll
            for (int dt = 0; dt < 4; ++dt) {
                const bf16x8 vf = *(const bf16x8*)swzVT(VTs, dt * 16 + l15, ks * 64 + l4 * 16);
                oacc[dt] = __builtin_amdgcn_mfma_f32_16x16x32_bf16(vf, pf, oacc[dt], 0, 0, 0);
            }
        }
        __builtin_amdgcn_s_setprio(0);
    }

    // ---- epilogue: bf16 unnormalized partial + (m,l) ----
    ushort* op = OP + (size_t)sp * TS * TH;
#pragma unroll
    for (int dt = 0; dt < 4; ++dt) {
        ushort4 o4;
        o4.x = f2bf_hw(oacc[dt][0]); o4.y = f2bf_hw(oacc[dt][1]);
        o4.z = f2bf_hw(oacc[dt][2]); o4.w = f2bf_hw(oacc[dt][3]);
        *(ushort4*)&op[(size_t)myq * TH + h * THD + dt * 16 + l4 * 4] = o4;
    }
    if (l4 == 0) {   // lanes sharing l15 hold identical (m,l) after the reduces
        float* ml = ML + (size_t)sp * TS * TNH * 2;
        ml[((size_t)myq * TNH + h) * 2 + 0] = m_run;
        ml[((size_t)myq * TNH + h) * 2 + 1] = l_run;
    }
}

// ---------------- flash combine of NSPLIT KV-split partials ----------------
__global__ __launch_bounds__(256) void attn_combine_kernel(
    const ushort* __restrict__ OP, const float* __restrict__ ML,
    ushort* __restrict__ O)
{
    const int idx = blockIdx.x * 256 + threadIdx.x;   // one ushort4 of one row
    const int row = idx >> 8;                         // 256 x 4 elems per row
    const int h = (idx & 255) >> 4;
    float m[NSPLIT], l[NSPLIT];
#pragma unroll
    for (int sp = 0; sp < NSPLIT; ++sp) {
        m[sp] = ML[((size_t)sp * TS * TNH + (size_t)row * TNH + h) * 2 + 0];
        l[sp] = ML[((size_t)sp * TS * TNH + (size_t)row * TNH + h) * 2 + 1];
    }
    float M = m[0];
#pragma unroll
    for (int sp = 1; sp < NSPLIT; ++sp) M = fmaxf(M, m[sp]);
    float w[NSPLIT], den = 0.f;
#pragma unroll
    for (int sp = 0; sp < NSPLIT; ++sp) {
        w[sp] = exp2f((m[sp] - M) * ATT_CE);
        den += l[sp] * w[sp];
    }
    const float inv = 1.f / den;
    float ax = 0.f, ay = 0.f, az = 0.f, aw = 0.f;
#pragma unroll
    for (int sp = 0; sp < NSPLIT; ++sp) {
        const ushort4 u = ((const ushort4*)(OP + (size_t)sp * TS * TH))[idx];
        ax += w[sp] * bf2f(u.x);
        ay += w[sp] * bf2f(u.y);
        az += w[sp] * bf2f(u.z);
        aw += w[sp] * bf2f(u.w);
    }
    ushort4 o;
    o.x = f2bf_hw(ax * inv);
    o.y = f2bf_hw(ay * inv);
    o.z = f2bf_hw(az * inv);
    o.w = f2bf_hw(aw * inv);
    ((ushort4*)O)[idx] = o;
}

// ---------------- launch ----------------
extern "C" void kernel_launch(void* const* d_in, const int* in_sizes, int n_in,
                              void* d_out, int out_size, void* d_ws, size_t ws_size,
                              hipStream_t stream)
{
    const float* x     = (const float*)d_in[0];
    const float* g1    = (const float*)d_in[1];
    const float* Wq    = (const float*)d_in[2];
    const float* bq    = (const float*)d_in[3];
    const float* Wdown = (const float*)d_in[4];
    const float* bdown = (const float*)d_in[5];
    const float* Wk    = (const float*)d_in[6];
    const float* bk    = (const float*)d_in[7];
    const float* Wv    = (const float*)d_in[8];
    const float* bv    = (const float*)d_in[9];
    const float* Wo    = (const float*)d_in[10];
    const float* bo    = (const float*)d_in[11];
    const float* g2    = (const float*)d_in[12];
    const float* W1    = (const float*)d_in[13];
    const float* b1    = (const float*)d_in[14];
    const float* W2    = (const float*)d_in[15];
    const float* b2    = (const float*)d_in[16];
    float* out = (float*)d_out;

    char* ws = (char*)d_ws;
    size_t off = 0;
    auto alloc = [&](size_t bytes) {
        void* p = ws + off;
        off += (bytes + 255) & ~(size_t)255;
        return p;
    };
    ushort* WqdT   = (ushort*)alloc((size_t)TQC * TD * 2);     // [1280][1024]
    ushort* WkvT   = (ushort*)alloc((size_t)2 * TH * TL * 2);  // [2048][256]
    ushort* WoT    = (ushort*)alloc((size_t)TD * TH * 2);
    ushort* W1T    = (ushort*)alloc((size_t)TDF * TD * 2);
    ushort* W2T    = (ushort*)alloc((size_t)TD * TDF * 2);
    float*  bkv    = (float*)alloc((size_t)2 * TH * 4);
    float*  bqd    = (float*)alloc((size_t)TQC * 4);
    ushort* hbuf   = (ushort*)alloc((size_t)TS * TD * 2);
    ushort* qcbuf  = (ushort*)alloc((size_t)TS * TQC * 2);     // [S][1280] = q|c
    ushort* kvbuf  = (ushort*)alloc((size_t)TS * 2 * TH * 2);  // [S][2048]
    ushort* obuf   = (ushort*)alloc((size_t)TS * TH * 2);
    float*  strm   = (float*)alloc((size_t)TS * TD * 4);
    ushort* h2buf  = (ushort*)alloc((size_t)TS * TD * 2);
    ushort* ffn1   = (ushort*)alloc((size_t)TS * TDF * 2);     // 16 MB
    float*  mlbuf  = (float*)alloc((size_t)NSPLIT * TS * TNH * 2 * 4);
    float*  psum   = (float*)alloc((size_t)2 * TS * TD * 4);   // W2 split-K partials
    // bf16 O-partials (NSPLIT x S x H x 2B = 16 MB) alias ffn1 (dead until W1).
    ushort* opart  = (ushort*)ffn1;

    // fused prologue: ALL transposes + bias concats + rmsnorm1, one dispatch
    prep_kernel<<<13069, 256, 0, stream>>>(
        x, g1, Wq, Wdown, Wk, Wv, Wo, W1, W2, bq, bdown, bk, bv,
        WqdT, WkvT, WoT, W1T, W2T, bkv, bqd, hbuf);

    // fused Wq|Wdown GEMM -> qcbuf [S][1280]
    gemm_bf16_kernel<0, 64, 64, 2, 1><<<dim3(TQC / 64, TS / 64), 256, 0, stream>>>(
        hbuf, WqdT, bqd, nullptr, qcbuf, TS, TQC, TD, TD);
    // Wk|Wv GEMM: A = c columns of qcbuf (stride 1280)
    gemm_bf16_kernel<0, 64, 64, 2, 1><<<dim3(2 * TH / 64, TS / 64), 256, 0, stream>>>(
        qcbuf + TH, WkvT, bkv, nullptr, kvbuf, TS, 2 * TH, TL, TQC);

    // attn: 8-wave QBLK=128 blocks, single-buffered K/V (32KB -> 4 blk/CU)
    mla_attn_kernel<<<dim3(TS / 128, TNH, NSPLIT), 512, 0, stream>>>(
        qcbuf, kvbuf, kvbuf + TH, opart, mlbuf);
    attn_combine_kernel<<<(TS * TH / 4) / 256, 256, 0, stream>>>(
        opart, mlbuf, obuf);

    gemm_bf16_kernel<2, 64, 64, 2, 1><<<dim3(TD / 64, TS / 64), 256, 0, stream>>>(
        obuf, WoT, bo, x, strm, TS, TD, TH, TH);

    rmsnorm_kernel<<<TS, 256, 0, stream>>>(strm, g2, h2buf, TD);

    // W1: 128x64 tile (1024 blocks = 4/CU)
    gemm_bf16_kernel<1, 128, 64, 1, 1><<<dim3(TDF / 64, TS / 128), 256, 0, stream>>>(
        h2buf, W1T, b1, nullptr, ffn1, TS, TDF, TD, TD);

    // W2 split-K x2 -> f32 partials, then fused bias+silu+resid combine
    gemm_bf16_kernel<4, 64, 64, 2, 2><<<dim3(TD / 64, TS / 64, 2), 256, 0, stream>>>(
        ffn1, W2T, nullptr, nullptr, psum, TS, TD, TDF, TDF);
    w2_combine_kernel<<<(TS * TD / 4) / 256, 256, 0, stream>>>(
        psum, b2, strm, out);
}